// Round 3
// baseline (510.042 us; speedup 1.0000x reference)
//
#include <hip/hip_runtime.h>
#include <hip/hip_bf16.h>

#define LSEQ 50
#define BATCH 4096

typedef __attribute__((ext_vector_type(8))) short bf16x8;
typedef __attribute__((ext_vector_type(4))) float f32x4;

__device__ __forceinline__ unsigned short f2bf(float f) {
    unsigned u = __builtin_bit_cast(unsigned, f);
    u += 0x7fffu + ((u >> 16) & 1u);
    return (unsigned short)(u >> 16);
}
__device__ __forceinline__ float fsigm(float x) {
    return __builtin_amdgcn_rcpf(1.0f + __builtin_amdgcn_exp2f(-1.44269504f * x));
}
__device__ __forceinline__ float ftanh(float x) {
    float e = __builtin_amdgcn_exp2f(2.88539008f * x);
    return 1.0f - 2.0f * __builtin_amdgcn_rcpf(e + 1.0f);
}

// One block = 8 examples, one direction. 1024 blocks -> 4 blocks/CU ->
// 4 waves/SIMD (was 2). MFMA M=16 tile half-wasted (rows 8-15 garbage,
// masked from all writes; LDS zeroed once so garbage stays finite/zero).
__global__ __launch_bounds__(256, 4)
void lstm_kernel(const float* __restrict__ rank_q, const int* __restrict__ qlen,
                 const float* __restrict__ Wih_f, const float* __restrict__ Whh_f,
                 const float* __restrict__ bih_f, const float* __restrict__ bhh_f,
                 const float* __restrict__ Wih_b, const float* __restrict__ Whh_b,
                 const float* __restrict__ bih_b, const float* __restrict__ bhh_b,
                 float* __restrict__ embq)
{
    const int blk = blockIdx.x;
    const int dir = blk >> 9;             // 0 = forward, 1 = backward
    const int b0  = (blk & 511) << 3;     // first of 8 examples
    const int tid = threadIdx.x;
    const int wv  = tid >> 6;
    const int ln  = tid & 63;
    const int lm  = ln & 15;
    const int lq  = ln >> 4;
    const int m   = (wv << 4) + lm;

    const float* Wih = dir ? Wih_b : Wih_f;
    const float* Whh = dir ? Whh_b : Whh_f;
    const float* bih = dir ? bih_b : bih_f;
    const float* bhh = dir ? bhh_b : bhh_f;

    __shared__ __align__(16) unsigned short xbuf[2][16][136];
    __shared__ __align__(16) unsigned short hbuf[2][16][72];

    // zero ALL of xbuf/hbuf once: rows 8-15 are never written afterwards,
    // so the wasted MFMA rows compute on zeros (finite), outputs masked.
    for (int i = tid; i < 2 * 16 * 136; i += 256) ((unsigned short*)xbuf)[i] = 0;
    for (int i = tid; i < 2 * 16 * 72;  i += 256) ((unsigned short*)hbuf)[i] = 0;

    bf16x8 bfrag[4][6];
    float bias[4];
    #pragma unroll
    for (int j = 0; j < 4; ++j) {
        const int n = (j << 6) + m;
        bias[j] = bih[n] + bhh[n];
        #pragma unroll
        for (int s = 0; s < 6; ++s) {
            const int kb = (s << 5) + (lq << 3);
            const float* src = (s < 4) ? (Wih + n * 128 + kb)
                                       : (Whh + n * 64 + (kb - 128));
            float4 w0 = *(const float4*)src;
            float4 w1 = *(const float4*)(src + 4);
            bf16x8 v;
            v[0]=(short)f2bf(w0.x); v[1]=(short)f2bf(w0.y);
            v[2]=(short)f2bf(w0.z); v[3]=(short)f2bf(w0.w);
            v[4]=(short)f2bf(w1.x); v[5]=(short)f2bf(w1.y);
            v[6]=(short)f2bf(w1.z); v[7]=(short)f2bf(w1.w);
            bfrag[j][s] = v;
        }
    }

    int len_e[4];
    #pragma unroll
    for (int r = 0; r < 4; ++r) {
        int idx = b0 + (lq << 2) + r;          // lq>=2 -> neighbor block's range
        len_e[r] = qlen[idx < BATCH ? idx : BATCH - 1];
    }

    float cst[4]  = {0.f, 0.f, 0.f, 0.f};
    float qval[4] = {0.f, 0.f, 0.f, 0.f};

    const int se = tid >> 4;             // staging example row (valid < 8)
    const int sd = (tid & 15) << 3;
    __syncthreads();                     // LDS zeros visible
    if (se < 8) {
        const int t0 = dir ? (LSEQ - 1) : 0;
        const float* src = rank_q + ((size_t)(b0 + se) * LSEQ + t0) * 128 + sd;
        float4 a = *(const float4*)src;
        float4 b = *(const float4*)(src + 4);
        bf16x8 v;
        v[0]=(short)f2bf(a.x); v[1]=(short)f2bf(a.y); v[2]=(short)f2bf(a.z); v[3]=(short)f2bf(a.w);
        v[4]=(short)f2bf(b.x); v[5]=(short)f2bf(b.y); v[6]=(short)f2bf(b.z); v[7]=(short)f2bf(b.w);
        *(bf16x8*)&xbuf[0][se][sd] = v;
    }
    __syncthreads();

    for (int it = 0; it < LSEQ; ++it) {
        const int t  = dir ? (LSEQ - 1 - it) : it;
        const int rb = it & 1;
        const int wb = rb ^ 1;

        bf16x8 ax0 = *(const bf16x8*)&xbuf[rb][lm][(lq << 3)];
        bf16x8 ax1 = *(const bf16x8*)&xbuf[rb][lm][32 + (lq << 3)];
        bf16x8 ax2 = *(const bf16x8*)&xbuf[rb][lm][64 + (lq << 3)];
        bf16x8 ax3 = *(const bf16x8*)&xbuf[rb][lm][96 + (lq << 3)];
        bf16x8 ah0 = *(const bf16x8*)&hbuf[rb][lm][(lq << 3)];
        bf16x8 ah1 = *(const bf16x8*)&hbuf[rb][lm][32 + (lq << 3)];

        float4 nx0, nx1;
        const bool pf = (se < 8) && (it + 1 < LSEQ);
        if (pf) {
            const int tn = dir ? (LSEQ - 2 - it) : (it + 1);
            const float* src = rank_q + ((size_t)(b0 + se) * LSEQ + tn) * 128 + sd;
            nx0 = *(const float4*)src;
            nx1 = *(const float4*)(src + 4);
        }

        f32x4 acc[4];
        #pragma unroll
        for (int j = 0; j < 4; ++j) {
            f32x4 a = {bias[j], bias[j], bias[j], bias[j]};
            a = __builtin_amdgcn_mfma_f32_16x16x32_bf16(ax0, bfrag[j][0], a, 0, 0, 0);
            a = __builtin_amdgcn_mfma_f32_16x16x32_bf16(ax1, bfrag[j][1], a, 0, 0, 0);
            a = __builtin_amdgcn_mfma_f32_16x16x32_bf16(ax2, bfrag[j][2], a, 0, 0, 0);
            a = __builtin_amdgcn_mfma_f32_16x16x32_bf16(ax3, bfrag[j][3], a, 0, 0, 0);
            a = __builtin_amdgcn_mfma_f32_16x16x32_bf16(ah0, bfrag[j][4], a, 0, 0, 0);
            a = __builtin_amdgcn_mfma_f32_16x16x32_bf16(ah1, bfrag[j][5], a, 0, 0, 0);
            acc[j] = a;
        }

        if (lq < 2) {                      // rows 8-15 are garbage: skip nonlin
            #pragma unroll
            for (int r = 0; r < 4; ++r) {
                float ig = fsigm(acc[0][r]);
                float fg = fsigm(acc[1][r]);
                float gg = ftanh(acc[2][r]);
                float og = fsigm(acc[3][r]);
                float cn = fg * cst[r] + ig * gg;
                cst[r] = cn;
                float hn = og * ftanh(cn);
                if (t == len_e[r] - 1) qval[r] = hn;
                hbuf[wb][(lq << 2) + r][m] = f2bf(hn);
            }
        }

        if (pf) {
            bf16x8 v;
            v[0]=(short)f2bf(nx0.x); v[1]=(short)f2bf(nx0.y); v[2]=(short)f2bf(nx0.z); v[3]=(short)f2bf(nx0.w);
            v[4]=(short)f2bf(nx1.x); v[5]=(short)f2bf(nx1.y); v[6]=(short)f2bf(nx1.z); v[7]=(short)f2bf(nx1.w);
            *(bf16x8*)&xbuf[wb][se][sd] = v;
        }
        __syncthreads();
    }

    if (lq < 2) {
        #pragma unroll
        for (int r = 0; r < 4; ++r)
            embq[(size_t)(b0 + (lq << 2) + r) * 128 + (dir << 6) + m] = qval[r];
    }
}

// ---- prep: transpose conv weights to [m][j][c][4] (coalesced lane=c reads)
__global__ __launch_bounds__(256)
void prep_kernel(const float* __restrict__ c1w, const float* __restrict__ c2w,
                 const float* __restrict__ c3w, float* __restrict__ T)
{
    const int id = blockIdx.x * 256 + threadIdx.x;   // 49152
    const int m  = id >> 13;
    const int rem = id & 8191;
    const int j  = rem >> 8;
    const int q  = rem & 255;
    const int c  = q >> 2;
    const int d  = (j << 2) + (q & 3);
    const float* src;
    switch (m) {
        case 0:  src = c1w + c * 128 + d;       break;
        case 1:  src = c2w + c * 256 + d;       break;
        case 2:  src = c2w + c * 256 + 128 + d; break;
        case 3:  src = c3w + c * 384 + d;       break;
        case 4:  src = c3w + c * 384 + 128 + d; break;
        default: src = c3w + c * 384 + 256 + d; break;
    }
    T[id] = *src;
}

__global__ __launch_bounds__(256)
void score_kernel(const int* __restrict__ r_idx, const int* __restrict__ a_idx,
                  const int* __restrict__ acc_idx,
                  const float* __restrict__ ru, const float* __restrict__ au,
                  const float* __restrict__ embq, const float* __restrict__ T,
                  const float* __restrict__ c1b, const float* __restrict__ c2b,
                  const float* __restrict__ c3b,
                  const float* __restrict__ fc1w, const float* __restrict__ fc2w,
                  float* __restrict__ diff)
{
    const int tid = threadIdx.x;
    const int wv  = tid >> 6;
    const int c   = tid & 63;
    const int b0  = blockIdx.x << 4;

    __shared__ __align__(16) float emb[64][132];
    {
        const int row = tid & 63;
        const int e   = row >> 2, v = row & 3;
        const int seg = (tid >> 6) << 5;
        const int bb  = b0 + e;
        const float* src = (v == 0) ? ru   + (size_t)r_idx[bb]   * 128 :
                           (v == 1) ? embq + (size_t)bb          * 128 :
                           (v == 2) ? au   + (size_t)a_idx[bb]   * 128 :
                                      au   + (size_t)acc_idx[bb] * 128;
        #pragma unroll
        for (int i = 0; i < 8; ++i) {
            float4 x = *(const float4*)(src + seg + (i << 2));
            *(float4*)&emb[row][seg + (i << 2)] = x;
        }
    }
    __syncthreads();

    float acc[4][9];
    #pragma unroll
    for (int e = 0; e < 4; ++e)
        #pragma unroll
        for (int k = 0; k < 9; ++k) acc[e][k] = 0.f;

    const float4* Tq = (const float4*)T;
    for (int j = 0; j < 32; ++j) {
        const float4* wq = Tq + j * 64 + c;
        const float4 w1  = wq[0];
        const float4 w20 = wq[2048];
        const float4 w21 = wq[4096];
        const float4 w30 = wq[6144];
        const float4 w31 = wq[8192];
        const float4 w32 = wq[10240];
        const int jd = j << 2;
        #pragma unroll
        for (int e = 0; e < 4; ++e) {
            const int br = ((wv << 2) + e) << 2;
            const float4 er = *(const float4*)&emb[br + 0][jd];
            const float4 eq = *(const float4*)&emb[br + 1][jd];
            const float4 ea = *(const float4*)&emb[br + 2][jd];
            const float4 ex = *(const float4*)&emb[br + 3][jd];
            acc[e][0] += w1.x*ea.x  + w1.y*ea.y  + w1.z*ea.z  + w1.w*ea.w;
            acc[e][1] += w1.x*ex.x  + w1.y*ex.y  + w1.z*ex.z  + w1.w*ex.w;
            acc[e][2] += w20.x*eq.x + w20.y*eq.y + w20.z*eq.z + w20.w*eq.w;
            acc[e][3] += w21.x*ea.x + w21.y*ea.y + w21.z*ea.z + w21.w*ea.w;
            acc[e][4] += w21.x*ex.x + w21.y*ex.y + w21.z*ex.z + w21.w*ex.w;
            acc[e][5] += w30.x*er.x + w30.y*er.y + w30.z*er.z + w30.w*er.w;
            acc[e][6] += w31.x*eq.x + w31.y*eq.y + w31.z*eq.z + w31.w*eq.w;
            acc[e][7] += w32.x*ea.x + w32.y*ea.y + w32.z*ea.z + w32.w*ea.w;
            acc[e][8] += w32.x*ex.x + w32.y*ex.y + w32.z*ex.z + w32.w*ex.w;
        }
    }

    const float b1 = c1b[c], b2 = c2b[c], b3 = c3b[c], f2 = fc2w[c];
    const float f12 = fc1w[2], f14 = fc1w[4], f15 = fc1w[5];
    #pragma unroll
    for (int e = 0; e < 4; ++e) {
        const float r1 = fmaxf(acc[e][0] + b1, 0.f) - fmaxf(acc[e][1] + b1, 0.f);
        const float r2 = fmaxf(acc[e][2] + acc[e][3] + b2, 0.f)
                       - fmaxf(acc[e][2] + acc[e][4] + b2, 0.f);
        const float r3 = fmaxf(acc[e][5] + acc[e][6] + acc[e][7] + b3, 0.f)
                       - fmaxf(acc[e][5] + acc[e][6] + acc[e][8] + b3, 0.f);
        float term = f2 * (f12 * r1 + f14 * r2 + f15 * r3);
        #pragma unroll
        for (int off = 32; off; off >>= 1) term += __shfl_down(term, off);
        if (c == 0) diff[b0 + (wv << 2) + e] = term;
    }
}

__global__ void reduce_kernel(const float* __restrict__ diff, float* __restrict__ out)
{
    __shared__ float s[256];
    const int tid = threadIdx.x;
    float v = 0.f;
    for (int i = tid; i < BATCH; i += 256) v += diff[i];
    s[tid] = v;
    __syncthreads();
    for (int st = 128; st > 0; st >>= 1) {
        if (tid < st) s[tid] += s[tid + st];
        __syncthreads();
    }
    if (tid == 0) out[0] = s[0];
}

extern "C" void kernel_launch(void* const* d_in, const int* in_sizes, int n_in,
                              void* d_out, int out_size, void* d_ws, size_t ws_size,
                              hipStream_t stream) {
    (void)in_sizes; (void)n_in; (void)out_size; (void)ws_size;
    const int*   r_idx   = (const int*)d_in[0];
    const int*   a_idx   = (const int*)d_in[1];
    const int*   acc_idx = (const int*)d_in[2];
    const float* rank_q  = (const float*)d_in[3];
    const int*   qlen    = (const int*)d_in[4];
    const float* ru      = (const float*)d_in[5];
    const float* au      = (const float*)d_in[6];
    const float* Wih_f   = (const float*)d_in[7];
    const float* Whh_f   = (const float*)d_in[8];
    const float* bih_f   = (const float*)d_in[9];
    const float* bhh_f   = (const float*)d_in[10];
    const float* Wih_b   = (const float*)d_in[11];
    const float* Whh_b   = (const float*)d_in[12];
    const float* bih_b   = (const float*)d_in[13];
    const float* bhh_b   = (const float*)d_in[14];
    const float* c1w     = (const float*)d_in[15];
    const float* c1b     = (const float*)d_in[16];
    const float* c2w     = (const float*)d_in[17];
    const float* c2b     = (const float*)d_in[18];
    const float* c3w     = (const float*)d_in[19];
    const float* c3b     = (const float*)d_in[20];
    const float* fc1w    = (const float*)d_in[21];
    const float* fc2w    = (const float*)d_in[23];

    float* embq = (float*)d_ws;                       // [4096][128] fp32
    float* diff = embq + (size_t)BATCH * 128;         // [4096]
    float* T    = diff + BATCH;                       // [49152]

    prep_kernel<<<192, 256, 0, stream>>>(c1w, c2w, c3w, T);
    lstm_kernel<<<1024, 256, 0, stream>>>(rank_q, qlen, Wih_f, Whh_f, bih_f, bhh_f,
                                          Wih_b, Whh_b, bih_b, bhh_b, embq);
    score_kernel<<<BATCH / 16, 256, 0, stream>>>(r_idx, a_idx, acc_idx, ru, au, embq, T,
                                                 c1b, c2b, c3b, fc1w, fc2w, diff);
    reduce_kernel<<<1, 256, 0, stream>>>(diff, (float*)d_out);
}

// Round 4
// 173.607 us; speedup vs baseline: 2.9379x; 2.9379x over previous
//
#include <hip/hip_runtime.h>
#include <hip/hip_bf16.h>

#define LSEQ 50
#define BATCH 4096

typedef __attribute__((ext_vector_type(8))) short bf16x8;
typedef __attribute__((ext_vector_type(4))) float f32x4;

__device__ __forceinline__ unsigned short f2bf(float f) {
    unsigned u = __builtin_bit_cast(unsigned, f);
    u += 0x7fffu + ((u >> 16) & 1u);
    return (unsigned short)(u >> 16);
}
__device__ __forceinline__ float fsigm(float x) {
    return __builtin_amdgcn_rcpf(1.0f + __builtin_amdgcn_exp2f(-1.44269504f * x));
}
__device__ __forceinline__ float ftanh(float x) {
    float e = __builtin_amdgcn_exp2f(2.88539008f * x);
    return 1.0f - 2.0f * __builtin_amdgcn_rcpf(e + 1.0f);
}

// One block = 8 examples, one direction; 1024 blocks. __launch_bounds__(256,2):
// compiler allocates 128 VGPR (R2-verified, no spill); 128 VGPR/wave allows
// 16 waves/CU -> 4 blocks/CU, so the 1024-block grid reaches 4 waves/SIMD
// naturally. (R3's (256,4) capped VGPR at 128 total incl. AGPR -> weight
// fragments spilled to scratch -> 1.3GB fetch. Never cap below the working set.)
__global__ __launch_bounds__(256, 2)
void lstm_kernel(const float* __restrict__ rank_q, const int* __restrict__ qlen,
                 const float* __restrict__ Wih_f, const float* __restrict__ Whh_f,
                 const float* __restrict__ bih_f, const float* __restrict__ bhh_f,
                 const float* __restrict__ Wih_b, const float* __restrict__ Whh_b,
                 const float* __restrict__ bih_b, const float* __restrict__ bhh_b,
                 float* __restrict__ embq)
{
    const int blk = blockIdx.x;
    const int dir = blk >> 9;             // 0 = forward, 1 = backward
    const int b0  = (blk & 511) << 3;     // first of 8 examples
    const int tid = threadIdx.x;
    const int wv  = tid >> 6;
    const int ln  = tid & 63;
    const int lm  = ln & 15;
    const int lq  = ln >> 4;
    const int m   = (wv << 4) + lm;

    const float* Wih = dir ? Wih_b : Wih_f;
    const float* Whh = dir ? Whh_b : Whh_f;
    const float* bih = dir ? bih_b : bih_f;
    const float* bhh = dir ? bhh_b : bhh_f;

    __shared__ __align__(16) unsigned short xbuf[2][16][136];
    __shared__ __align__(16) unsigned short hbuf[2][16][72];

    // zero ALL of xbuf/hbuf once: rows 8-15 never written afterwards, so the
    // wasted MFMA rows compute on zeros (finite), outputs masked.
    for (int i = tid; i < 2 * 16 * 136; i += 256) ((unsigned short*)xbuf)[i] = 0;
    for (int i = tid; i < 2 * 16 * 72;  i += 256) ((unsigned short*)hbuf)[i] = 0;

    bf16x8 bfrag[4][6];
    float bias[4];
    #pragma unroll
    for (int j = 0; j < 4; ++j) {
        const int n = (j << 6) + m;
        bias[j] = bih[n] + bhh[n];
        #pragma unroll
        for (int s = 0; s < 6; ++s) {
            const int kb = (s << 5) + (lq << 3);
            const float* src = (s < 4) ? (Wih + n * 128 + kb)
                                       : (Whh + n * 64 + (kb - 128));
            float4 w0 = *(const float4*)src;
            float4 w1 = *(const float4*)(src + 4);
            bf16x8 v;
            v[0]=(short)f2bf(w0.x); v[1]=(short)f2bf(w0.y);
            v[2]=(short)f2bf(w0.z); v[3]=(short)f2bf(w0.w);
            v[4]=(short)f2bf(w1.x); v[5]=(short)f2bf(w1.y);
            v[6]=(short)f2bf(w1.z); v[7]=(short)f2bf(w1.w);
            bfrag[j][s] = v;
        }
    }

    int len_e[4];
    #pragma unroll
    for (int r = 0; r < 4; ++r) {
        int idx = b0 + (lq << 2) + r;          // lq>=2 -> clamped (masked out)
        len_e[r] = qlen[idx < BATCH ? idx : BATCH - 1];
    }

    float cst[4]  = {0.f, 0.f, 0.f, 0.f};
    float qval[4] = {0.f, 0.f, 0.f, 0.f};

    const int se = tid >> 4;             // staging example row (valid < 8)
    const int sd = (tid & 15) << 3;
    __syncthreads();                     // LDS zeros visible
    if (se < 8) {
        const int t0 = dir ? (LSEQ - 1) : 0;
        const float* src = rank_q + ((size_t)(b0 + se) * LSEQ + t0) * 128 + sd;
        float4 a = *(const float4*)src;
        float4 b = *(const float4*)(src + 4);
        bf16x8 v;
        v[0]=(short)f2bf(a.x); v[1]=(short)f2bf(a.y); v[2]=(short)f2bf(a.z); v[3]=(short)f2bf(a.w);
        v[4]=(short)f2bf(b.x); v[5]=(short)f2bf(b.y); v[6]=(short)f2bf(b.z); v[7]=(short)f2bf(b.w);
        *(bf16x8*)&xbuf[0][se][sd] = v;
    }
    __syncthreads();

    for (int it = 0; it < LSEQ; ++it) {
        const int t  = dir ? (LSEQ - 1 - it) : it;
        const int rb = it & 1;
        const int wb = rb ^ 1;

        bf16x8 ax0 = *(const bf16x8*)&xbuf[rb][lm][(lq << 3)];
        bf16x8 ax1 = *(const bf16x8*)&xbuf[rb][lm][32 + (lq << 3)];
        bf16x8 ax2 = *(const bf16x8*)&xbuf[rb][lm][64 + (lq << 3)];
        bf16x8 ax3 = *(const bf16x8*)&xbuf[rb][lm][96 + (lq << 3)];
        bf16x8 ah0 = *(const bf16x8*)&hbuf[rb][lm][(lq << 3)];
        bf16x8 ah1 = *(const bf16x8*)&hbuf[rb][lm][32 + (lq << 3)];

        float4 nx0, nx1;
        const bool pf = (se < 8) && (it + 1 < LSEQ);
        if (pf) {
            const int tn = dir ? (LSEQ - 2 - it) : (it + 1);
            const float* src = rank_q + ((size_t)(b0 + se) * LSEQ + tn) * 128 + sd;
            nx0 = *(const float4*)src;
            nx1 = *(const float4*)(src + 4);
        }

        f32x4 acc[4];
        #pragma unroll
        for (int j = 0; j < 4; ++j) {
            f32x4 a = {bias[j], bias[j], bias[j], bias[j]};
            a = __builtin_amdgcn_mfma_f32_16x16x32_bf16(ax0, bfrag[j][0], a, 0, 0, 0);
            a = __builtin_amdgcn_mfma_f32_16x16x32_bf16(ax1, bfrag[j][1], a, 0, 0, 0);
            a = __builtin_amdgcn_mfma_f32_16x16x32_bf16(ax2, bfrag[j][2], a, 0, 0, 0);
            a = __builtin_amdgcn_mfma_f32_16x16x32_bf16(ax3, bfrag[j][3], a, 0, 0, 0);
            a = __builtin_amdgcn_mfma_f32_16x16x32_bf16(ah0, bfrag[j][4], a, 0, 0, 0);
            a = __builtin_amdgcn_mfma_f32_16x16x32_bf16(ah1, bfrag[j][5], a, 0, 0, 0);
            acc[j] = a;
        }

        if (lq < 2) {                      // rows 8-15 are garbage: skip nonlin
            #pragma unroll
            for (int r = 0; r < 4; ++r) {
                float ig = fsigm(acc[0][r]);
                float fg = fsigm(acc[1][r]);
                float gg = ftanh(acc[2][r]);
                float og = fsigm(acc[3][r]);
                float cn = fg * cst[r] + ig * gg;
                cst[r] = cn;
                float hn = og * ftanh(cn);
                if (t == len_e[r] - 1) qval[r] = hn;
                hbuf[wb][(lq << 2) + r][m] = f2bf(hn);
            }
        }

        if (pf) {
            bf16x8 v;
            v[0]=(short)f2bf(nx0.x); v[1]=(short)f2bf(nx0.y); v[2]=(short)f2bf(nx0.z); v[3]=(short)f2bf(nx0.w);
            v[4]=(short)f2bf(nx1.x); v[5]=(short)f2bf(nx1.y); v[6]=(short)f2bf(nx1.z); v[7]=(short)f2bf(nx1.w);
            *(bf16x8*)&xbuf[wb][se][sd] = v;
        }
        __syncthreads();
    }

    if (lq < 2) {
        #pragma unroll
        for (int r = 0; r < 4; ++r)
            embq[(size_t)(b0 + (lq << 2) + r) * 128 + (dir << 6) + m] = qval[r];
    }
}

// ---- prep: transpose conv weights to [m][j][c][4] (coalesced lane=c reads)
__global__ __launch_bounds__(256)
void prep_kernel(const float* __restrict__ c1w, const float* __restrict__ c2w,
                 const float* __restrict__ c3w, float* __restrict__ T)
{
    const int id = blockIdx.x * 256 + threadIdx.x;   // 49152
    const int m  = id >> 13;
    const int rem = id & 8191;
    const int j  = rem >> 8;
    const int q  = rem & 255;
    const int c  = q >> 2;
    const int d  = (j << 2) + (q & 3);
    const float* src;
    switch (m) {
        case 0:  src = c1w + c * 128 + d;       break;
        case 1:  src = c2w + c * 256 + d;       break;
        case 2:  src = c2w + c * 256 + 128 + d; break;
        case 3:  src = c3w + c * 384 + d;       break;
        case 4:  src = c3w + c * 384 + 128 + d; break;
        default: src = c3w + c * 384 + 256 + d; break;
    }
    T[id] = *src;
}

__global__ __launch_bounds__(256)
void score_kernel(const int* __restrict__ r_idx, const int* __restrict__ a_idx,
                  const int* __restrict__ acc_idx,
                  const float* __restrict__ ru, const float* __restrict__ au,
                  const float* __restrict__ embq, const float* __restrict__ T,
                  const float* __restrict__ c1b, const float* __restrict__ c2b,
                  const float* __restrict__ c3b,
                  const float* __restrict__ fc1w, const float* __restrict__ fc2w,
                  float* __restrict__ diff)
{
    const int tid = threadIdx.x;
    const int wv  = tid >> 6;
    const int c   = tid & 63;
    const int b0  = blockIdx.x << 4;

    __shared__ __align__(16) float emb[64][132];
    {
        const int row = tid & 63;
        const int e   = row >> 2, v = row & 3;
        const int seg = (tid >> 6) << 5;
        const int bb  = b0 + e;
        const float* src = (v == 0) ? ru   + (size_t)r_idx[bb]   * 128 :
                           (v == 1) ? embq + (size_t)bb          * 128 :
                           (v == 2) ? au   + (size_t)a_idx[bb]   * 128 :
                                      au   + (size_t)acc_idx[bb] * 128;
        #pragma unroll
        for (int i = 0; i < 8; ++i) {
            float4 x = *(const float4*)(src + seg + (i << 2));
            *(float4*)&emb[row][seg + (i << 2)] = x;
        }
    }
    __syncthreads();

    float acc[4][9];
    #pragma unroll
    for (int e = 0; e < 4; ++e)
        #pragma unroll
        for (int k = 0; k < 9; ++k) acc[e][k] = 0.f;

    const float4* Tq = (const float4*)T;
    for (int j = 0; j < 32; ++j) {
        const float4* wq = Tq + j * 64 + c;
        const float4 w1  = wq[0];
        const float4 w20 = wq[2048];
        const float4 w21 = wq[4096];
        const float4 w30 = wq[6144];
        const float4 w31 = wq[8192];
        const float4 w32 = wq[10240];
        const int jd = j << 2;
        #pragma unroll
        for (int e = 0; e < 4; ++e) {
            const int br = ((wv << 2) + e) << 2;
            const float4 er = *(const float4*)&emb[br + 0][jd];
            const float4 eq = *(const float4*)&emb[br + 1][jd];
            const float4 ea = *(const float4*)&emb[br + 2][jd];
            const float4 ex = *(const float4*)&emb[br + 3][jd];
            acc[e][0] += w1.x*ea.x  + w1.y*ea.y  + w1.z*ea.z  + w1.w*ea.w;
            acc[e][1] += w1.x*ex.x  + w1.y*ex.y  + w1.z*ex.z  + w1.w*ex.w;
            acc[e][2] += w20.x*eq.x + w20.y*eq.y + w20.z*eq.z + w20.w*eq.w;
            acc[e][3] += w21.x*ea.x + w21.y*ea.y + w21.z*ea.z + w21.w*ea.w;
            acc[e][4] += w21.x*ex.x + w21.y*ex.y + w21.z*ex.z + w21.w*ex.w;
            acc[e][5] += w30.x*er.x + w30.y*er.y + w30.z*er.z + w30.w*er.w;
            acc[e][6] += w31.x*eq.x + w31.y*eq.y + w31.z*eq.z + w31.w*eq.w;
            acc[e][7] += w32.x*ea.x + w32.y*ea.y + w32.z*ea.z + w32.w*ea.w;
            acc[e][8] += w32.x*ex.x + w32.y*ex.y + w32.z*ex.z + w32.w*ex.w;
        }
    }

    const float b1 = c1b[c], b2 = c2b[c], b3 = c3b[c], f2 = fc2w[c];
    const float f12 = fc1w[2], f14 = fc1w[4], f15 = fc1w[5];
    #pragma unroll
    for (int e = 0; e < 4; ++e) {
        const float r1 = fmaxf(acc[e][0] + b1, 0.f) - fmaxf(acc[e][1] + b1, 0.f);
        const float r2 = fmaxf(acc[e][2] + acc[e][3] + b2, 0.f)
                       - fmaxf(acc[e][2] + acc[e][4] + b2, 0.f);
        const float r3 = fmaxf(acc[e][5] + acc[e][6] + acc[e][7] + b3, 0.f)
                       - fmaxf(acc[e][5] + acc[e][6] + acc[e][8] + b3, 0.f);
        float term = f2 * (f12 * r1 + f14 * r2 + f15 * r3);
        #pragma unroll
        for (int off = 32; off; off >>= 1) term += __shfl_down(term, off);
        if (c == 0) diff[b0 + (wv << 2) + e] = term;
    }
}

__global__ void reduce_kernel(const float* __restrict__ diff, float* __restrict__ out)
{
    __shared__ float s[256];
    const int tid = threadIdx.x;
    float v = 0.f;
    for (int i = tid; i < BATCH; i += 256) v += diff[i];
    s[tid] = v;
    __syncthreads();
    for (int st = 128; st > 0; st >>= 1) {
        if (tid < st) s[tid] += s[tid + st];
        __syncthreads();
    }
    if (tid == 0) out[0] = s[0];
}

extern "C" void kernel_launch(void* const* d_in, const int* in_sizes, int n_in,
                              void* d_out, int out_size, void* d_ws, size_t ws_size,
                              hipStream_t stream) {
    (void)in_sizes; (void)n_in; (void)out_size; (void)ws_size;
    const int*   r_idx   = (const int*)d_in[0];
    const int*   a_idx   = (const int*)d_in[1];
    const int*   acc_idx = (const int*)d_in[2];
    const float* rank_q  = (const float*)d_in[3];
    const int*   qlen    = (const int*)d_in[4];
    const float* ru      = (const float*)d_in[5];
    const float* au      = (const float*)d_in[6];
    const float* Wih_f   = (const float*)d_in[7];
    const float* Whh_f   = (const float*)d_in[8];
    const float* bih_f   = (const float*)d_in[9];
    const float* bhh_f   = (const float*)d_in[10];
    const float* Wih_b   = (const float*)d_in[11];
    const float* Whh_b   = (const float*)d_in[12];
    const float* bih_b   = (const float*)d_in[13];
    const float* bhh_b   = (const float*)d_in[14];
    const float* c1w     = (const float*)d_in[15];
    const float* c1b     = (const float*)d_in[16];
    const float* c2w     = (const float*)d_in[17];
    const float* c2b     = (const float*)d_in[18];
    const float* c3w     = (const float*)d_in[19];
    const float* c3b     = (const float*)d_in[20];
    const float* fc1w    = (const float*)d_in[21];
    const float* fc2w    = (const float*)d_in[23];

    float* embq = (float*)d_ws;                       // [4096][128] fp32
    float* diff = embq + (size_t)BATCH * 128;         // [4096]
    float* T    = diff + BATCH;                       // [49152]

    prep_kernel<<<192, 256, 0, stream>>>(c1w, c2w, c3w, T);
    lstm_kernel<<<1024, 256, 0, stream>>>(rank_q, qlen, Wih_f, Whh_f, bih_f, bhh_f,
                                          Wih_b, Whh_b, bih_b, bhh_b, embq);
    score_kernel<<<BATCH / 16, 256, 0, stream>>>(r_idx, a_idx, acc_idx, ru, au, embq, T,
                                                 c1b, c2b, c3b, fc1w, fc2w, diff);
    reduce_kernel<<<1, 256, 0, stream>>>(diff, (float*)d_out);
}

// Round 5
// 96.773 us; speedup vs baseline: 5.2705x; 1.7940x over previous
//
#include <hip/hip_runtime.h>
#include <hip/hip_bf16.h>

#define LSEQ 50
#define BATCH 4096

typedef __attribute__((ext_vector_type(8))) short bf16x8;
typedef __attribute__((ext_vector_type(4))) float f32x4;

__device__ __forceinline__ unsigned cvtpk(float lo, float hi) {
    unsigned r;
    asm("v_cvt_pk_bf16_f32 %0, %1, %2" : "=v"(r) : "v"(lo), "v"(hi));
    return r;
}
__device__ __forceinline__ bf16x8 pack8(float4 a, float4 b) {
    uint4 u;
    u.x = cvtpk(a.x, a.y); u.y = cvtpk(a.z, a.w);
    u.z = cvtpk(b.x, b.y); u.w = cvtpk(b.z, b.w);
    return __builtin_bit_cast(bf16x8, u);
}
__device__ __forceinline__ float fsigm(float x) {
    return __builtin_amdgcn_rcpf(1.0f + __builtin_amdgcn_exp2f(-1.44269504f * x));
}
__device__ __forceinline__ float ftanh(float x) {
    float e = __builtin_amdgcn_exp2f(2.88539008f * x);
    return 1.0f - 2.0f * __builtin_amdgcn_rcpf(e + 1.0f);
}

// One block = 16 examples, one direction (R2 structure, 512 blocks,
// 2 blocks/CU — register-pinned at 192 regs/wave incl. acc, so occupancy
// can't rise; instead the x-GEMM is software-pipelined one step ahead
// (triple-buffered x) so the per-step serial chain is only the 2-MFMA
// h-part + nonlinearity. Conversions use v_cvt_pk_bf16_f32 (RNE, same
// rounding as before).
__global__ __launch_bounds__(256, 2)
void lstm_kernel(const float* __restrict__ rank_q, const int* __restrict__ qlen,
                 const float* __restrict__ Wih_f, const float* __restrict__ Whh_f,
                 const float* __restrict__ bih_f, const float* __restrict__ bhh_f,
                 const float* __restrict__ Wih_b, const float* __restrict__ Whh_b,
                 const float* __restrict__ bih_b, const float* __restrict__ bhh_b,
                 float* __restrict__ embq)
{
    const int blk = blockIdx.x;
    const int dir = blk >> 8;             // 0 = forward, 1 = backward
    const int b0  = (blk & 255) << 4;     // first of 16 examples
    const int tid = threadIdx.x;
    const int wv  = tid >> 6;
    const int ln  = tid & 63;
    const int lm  = ln & 15;
    const int lq  = ln >> 4;
    const int m   = (wv << 4) + lm;

    const float* Wih = dir ? Wih_b : Wih_f;
    const float* Whh = dir ? Whh_b : Whh_f;
    const float* bih = dir ? bih_b : bih_f;
    const float* bhh = dir ? bhh_b : bhh_f;

    __shared__ __align__(16) unsigned short xbuf[3][16][136];  // triple buffer
    __shared__ __align__(16) unsigned short hbuf[2][16][72];

    bf16x8 bfrag[4][6];
    float bias[4];
    #pragma unroll
    for (int j = 0; j < 4; ++j) {
        const int n = (j << 6) + m;
        bias[j] = bih[n] + bhh[n];
        #pragma unroll
        for (int s = 0; s < 6; ++s) {
            const int kb = (s << 5) + (lq << 3);
            const float* src = (s < 4) ? (Wih + n * 128 + kb)
                                       : (Whh + n * 64 + (kb - 128));
            bfrag[j][s] = pack8(*(const float4*)src, *(const float4*)(src + 4));
        }
    }

    int len_e[4];
    #pragma unroll
    for (int r = 0; r < 4; ++r) len_e[r] = qlen[b0 + (lq << 2) + r];

    float cst[4]  = {0.f, 0.f, 0.f, 0.f};
    float qval[4] = {0.f, 0.f, 0.f, 0.f};

    // zero hbuf[0] (initial h = 0); hbuf[1]/xbuf fully written before reads
    for (int i = tid; i < 16 * 72; i += 256) ((unsigned short*)hbuf)[i] = 0;

    // staging: thread -> (example se, 8-float chunk sd); stepping pointer
    const int se = tid >> 4;
    const int sd = (tid & 15) << 3;
    const int tstep = dir ? -128 : 128;
    const float* gp = rank_q + ((size_t)(b0 + se) * LSEQ + (dir ? LSEQ - 1 : 0)) * 128 + sd;

    {   // stage x(it=0) -> xbuf[0], x(it=1) -> xbuf[1]
        float4 a0 = *(const float4*)gp, b0v = *(const float4*)(gp + 4); gp += tstep;
        float4 a1 = *(const float4*)gp, b1v = *(const float4*)(gp + 4); gp += tstep;
        *(bf16x8*)&xbuf[0][se][sd] = pack8(a0, b0v);
        *(bf16x8*)&xbuf[1][se][sd] = pack8(a1, b1v);
    }
    __syncthreads();

    const int xoff = lm * 136 + (lq << 3);
    const int hoff = lm * 72 + (lq << 3);

    // prologue: acc_x for it=0 from xbuf[0]
    f32x4 accx[4];
    {
        const unsigned short* xb = &xbuf[0][0][0];
        bf16x8 x0 = *(const bf16x8*)(xb + xoff);
        bf16x8 x1 = *(const bf16x8*)(xb + xoff + 32);
        bf16x8 x2 = *(const bf16x8*)(xb + xoff + 64);
        bf16x8 x3 = *(const bf16x8*)(xb + xoff + 96);
        #pragma unroll
        for (int j = 0; j < 4; ++j) {
            f32x4 a = {bias[j], bias[j], bias[j], bias[j]};
            a = __builtin_amdgcn_mfma_f32_16x16x32_bf16(x0, bfrag[j][0], a, 0, 0, 0);
            a = __builtin_amdgcn_mfma_f32_16x16x32_bf16(x1, bfrag[j][1], a, 0, 0, 0);
            a = __builtin_amdgcn_mfma_f32_16x16x32_bf16(x2, bfrag[j][2], a, 0, 0, 0);
            a = __builtin_amdgcn_mfma_f32_16x16x32_bf16(x3, bfrag[j][3], a, 0, 0, 0);
            accx[j] = a;
        }
    }

    int r1 = 1, w2 = 2;                    // xbuf indices: read x(it+1), write x(it+2)
    for (int it = 0; it < LSEQ; ++it) {
        const int t   = dir ? (LSEQ - 1 - it) : it;
        const int rbh = it & 1;
        const int wbh = rbh ^ 1;

        // global prefetch of x(it+2) (issued early; stored after nonlin)
        float4 nxa, nxb;
        const bool pf = (it <= LSEQ - 3);
        if (pf) { nxa = *(const float4*)gp; nxb = *(const float4*)(gp + 4); gp += tstep; }

        // h-part: 2-deep MFMA chain on top of pipelined acc_x (critical path)
        const unsigned short* hb = &hbuf[rbh][0][0];
        bf16x8 ah0 = *(const bf16x8*)(hb + hoff);
        bf16x8 ah1 = *(const bf16x8*)(hb + hoff + 32);
        f32x4 gate[4];
        #pragma unroll
        for (int j = 0; j < 4; ++j) {
            f32x4 a = __builtin_amdgcn_mfma_f32_16x16x32_bf16(ah0, bfrag[j][4], accx[j], 0, 0, 0);
            gate[j]  = __builtin_amdgcn_mfma_f32_16x16x32_bf16(ah1, bfrag[j][5], a, 0, 0, 0);
        }

        // acc_x for it+1 (independent; fills the nonlin/stall shadow)
        if (it + 1 < LSEQ) {
            const unsigned short* xb = &xbuf[r1][0][0];
            bf16x8 x0 = *(const bf16x8*)(xb + xoff);
            bf16x8 x1 = *(const bf16x8*)(xb + xoff + 32);
            bf16x8 x2 = *(const bf16x8*)(xb + xoff + 64);
            bf16x8 x3 = *(const bf16x8*)(xb + xoff + 96);
            #pragma unroll
            for (int j = 0; j < 4; ++j) {
                f32x4 a = {bias[j], bias[j], bias[j], bias[j]};
                a = __builtin_amdgcn_mfma_f32_16x16x32_bf16(x0, bfrag[j][0], a, 0, 0, 0);
                a = __builtin_amdgcn_mfma_f32_16x16x32_bf16(x1, bfrag[j][1], a, 0, 0, 0);
                a = __builtin_amdgcn_mfma_f32_16x16x32_bf16(x2, bfrag[j][2], a, 0, 0, 0);
                a = __builtin_amdgcn_mfma_f32_16x16x32_bf16(x3, bfrag[j][3], a, 0, 0, 0);
                accx[j] = a;
            }
        }

        // nonlinearity + state update (all 16 rows valid)
        float hn[4];
        #pragma unroll
        for (int r = 0; r < 4; ++r) {
            float ig = fsigm(gate[0][r]);
            float fg = fsigm(gate[1][r]);
            float gg = ftanh(gate[2][r]);
            float og = fsigm(gate[3][r]);
            float cn = fg * cst[r] + ig * gg;
            cst[r] = cn;
            hn[r] = og * ftanh(cn);
            if (t == len_e[r] - 1) qval[r] = hn[r];
        }
        const unsigned u01 = cvtpk(hn[0], hn[1]);
        const unsigned u23 = cvtpk(hn[2], hn[3]);
        hbuf[wbh][(lq << 2) + 0][m] = (unsigned short)u01;
        hbuf[wbh][(lq << 2) + 1][m] = (unsigned short)(u01 >> 16);
        hbuf[wbh][(lq << 2) + 2][m] = (unsigned short)u23;
        hbuf[wbh][(lq << 2) + 3][m] = (unsigned short)(u23 >> 16);

        if (pf) *(bf16x8*)&xbuf[w2][se][sd] = pack8(nxa, nxb);

        __syncthreads();
        r1 = (r1 == 2) ? 0 : r1 + 1;
        w2 = (w2 == 2) ? 0 : w2 + 1;
    }

    #pragma unroll
    for (int r = 0; r < 4; ++r)
        embq[(size_t)(b0 + (lq << 2) + r) * 128 + (dir << 6) + m] = qval[r];
}

// ---- prep: transpose conv weights to [m][j][c][4] (coalesced lane=c reads)
__global__ __launch_bounds__(256)
void prep_kernel(const float* __restrict__ c1w, const float* __restrict__ c2w,
                 const float* __restrict__ c3w, float* __restrict__ T)
{
    const int id = blockIdx.x * 256 + threadIdx.x;   // 49152
    const int m  = id >> 13;
    const int rem = id & 8191;
    const int j  = rem >> 8;
    const int q  = rem & 255;
    const int c  = q >> 2;
    const int d  = (j << 2) + (q & 3);
    const float* src;
    switch (m) {
        case 0:  src = c1w + c * 128 + d;       break;
        case 1:  src = c2w + c * 256 + d;       break;
        case 2:  src = c2w + c * 256 + 128 + d; break;
        case 3:  src = c3w + c * 384 + d;       break;
        case 4:  src = c3w + c * 384 + 128 + d; break;
        default: src = c3w + c * 384 + 256 + d; break;
    }
    T[id] = *src;
}

__global__ __launch_bounds__(256)
void score_kernel(const int* __restrict__ r_idx, const int* __restrict__ a_idx,
                  const int* __restrict__ acc_idx,
                  const float* __restrict__ ru, const float* __restrict__ au,
                  const float* __restrict__ embq, const float* __restrict__ T,
                  const float* __restrict__ c1b, const float* __restrict__ c2b,
                  const float* __restrict__ c3b,
                  const float* __restrict__ fc1w, const float* __restrict__ fc2w,
                  float* __restrict__ diff)
{
    const int tid = threadIdx.x;
    const int wv  = tid >> 6;
    const int c   = tid & 63;
    const int b0  = blockIdx.x << 4;

    __shared__ __align__(16) float emb[64][132];
    {
        const int row = tid & 63;
        const int e   = row >> 2, v = row & 3;
        const int seg = (tid >> 6) << 5;
        const int bb  = b0 + e;
        const float* src = (v == 0) ? ru   + (size_t)r_idx[bb]   * 128 :
                           (v == 1) ? embq + (size_t)bb          * 128 :
                           (v == 2) ? au   + (size_t)a_idx[bb]   * 128 :
                                      au   + (size_t)acc_idx[bb] * 128;
        #pragma unroll
        for (int i = 0; i < 8; ++i) {
            float4 x = *(const float4*)(src + seg + (i << 2));
            *(float4*)&emb[row][seg + (i << 2)] = x;
        }
    }
    __syncthreads();

    float acc[4][9];
    #pragma unroll
    for (int e = 0; e < 4; ++e)
        #pragma unroll
        for (int k = 0; k < 9; ++k) acc[e][k] = 0.f;

    const float4* Tq = (const float4*)T;
    for (int j = 0; j < 32; ++j) {
        const float4* wq = Tq + j * 64 + c;
        const float4 w1  = wq[0];
        const float4 w20 = wq[2048];
        const float4 w21 = wq[4096];
        const float4 w30 = wq[6144];
        const float4 w31 = wq[8192];
        const float4 w32 = wq[10240];
        const int jd = j << 2;
        #pragma unroll
        for (int e = 0; e < 4; ++e) {
            const int br = ((wv << 2) + e) << 2;
            const float4 er = *(const float4*)&emb[br + 0][jd];
            const float4 eq = *(const float4*)&emb[br + 1][jd];
            const float4 ea = *(const float4*)&emb[br + 2][jd];
            const float4 ex = *(const float4*)&emb[br + 3][jd];
            acc[e][0] += w1.x*ea.x  + w1.y*ea.y  + w1.z*ea.z  + w1.w*ea.w;
            acc[e][1] += w1.x*ex.x  + w1.y*ex.y  + w1.z*ex.z  + w1.w*ex.w;
            acc[e][2] += w20.x*eq.x + w20.y*eq.y + w20.z*eq.z + w20.w*eq.w;
            acc[e][3] += w21.x*ea.x + w21.y*ea.y + w21.z*ea.z + w21.w*ea.w;
            acc[e][4] += w21.x*ex.x + w21.y*ex.y + w21.z*ex.z + w21.w*ex.w;
            acc[e][5] += w30.x*er.x + w30.y*er.y + w30.z*er.z + w30.w*er.w;
            acc[e][6] += w31.x*eq.x + w31.y*eq.y + w31.z*eq.z + w31.w*eq.w;
            acc[e][7] += w32.x*ea.x + w32.y*ea.y + w32.z*ea.z + w32.w*ea.w;
            acc[e][8] += w32.x*ex.x + w32.y*ex.y + w32.z*ex.z + w32.w*ex.w;
        }
    }

    const float b1 = c1b[c], b2 = c2b[c], b3 = c3b[c], f2 = fc2w[c];
    const float f12 = fc1w[2], f14 = fc1w[4], f15 = fc1w[5];
    #pragma unroll
    for (int e = 0; e < 4; ++e) {
        const float r1 = fmaxf(acc[e][0] + b1, 0.f) - fmaxf(acc[e][1] + b1, 0.f);
        const float r2 = fmaxf(acc[e][2] + acc[e][3] + b2, 0.f)
                       - fmaxf(acc[e][2] + acc[e][4] + b2, 0.f);
        const float r3 = fmaxf(acc[e][5] + acc[e][6] + acc[e][7] + b3, 0.f)
                       - fmaxf(acc[e][5] + acc[e][6] + acc[e][8] + b3, 0.f);
        float term = f2 * (f12 * r1 + f14 * r2 + f15 * r3);
        #pragma unroll
        for (int off = 32; off; off >>= 1) term += __shfl_down(term, off);
        if (c == 0) diff[b0 + (wv << 2) + e] = term;
    }
}

__global__ void reduce_kernel(const float* __restrict__ diff, float* __restrict__ out)
{
    __shared__ float s[256];
    const int tid = threadIdx.x;
    float v = 0.f;
    for (int i = tid; i < BATCH; i += 256) v += diff[i];
    s[tid] = v;
    __syncthreads();
    for (int st = 128; st > 0; st >>= 1) {
        if (tid < st) s[tid] += s[tid + st];
        __syncthreads();
    }
    if (tid == 0) out[0] = s[0];
}

extern "C" void kernel_launch(void* const* d_in, const int* in_sizes, int n_in,
                              void* d_out, int out_size, void* d_ws, size_t ws_size,
                              hipStream_t stream) {
    (void)in_sizes; (void)n_in; (void)out_size; (void)ws_size;
    const int*   r_idx   = (const int*)d_in[0];
    const int*   a_idx   = (const int*)d_in[1];
    const int*   acc_idx = (const int*)d_in[2];
    const float* rank_q  = (const float*)d_in[3];
    const int*   qlen    = (const int*)d_in[4];
    const float* ru      = (const float*)d_in[5];
    const float* au      = (const float*)d_in[6];
    const float* Wih_f   = (const float*)d_in[7];
    const float* Whh_f   = (const float*)d_in[8];
    const float* bih_f   = (const float*)d_in[9];
    const float* bhh_f   = (const float*)d_in[10];
    const float* Wih_b   = (const float*)d_in[11];
    const float* Whh_b   = (const float*)d_in[12];
    const float* bih_b   = (const float*)d_in[13];
    const float* bhh_b   = (const float*)d_in[14];
    const float* c1w     = (const float*)d_in[15];
    const float* c1b     = (const float*)d_in[16];
    const float* c2w     = (const float*)d_in[17];
    const float* c2b     = (const float*)d_in[18];
    const float* c3w     = (const float*)d_in[19];
    const float* c3b     = (const float*)d_in[20];
    const float* fc1w    = (const float*)d_in[21];
    const float* fc2w    = (const float*)d_in[23];

    float* embq = (float*)d_ws;                       // [4096][128] fp32
    float* diff = embq + (size_t)BATCH * 128;         // [4096]
    float* T    = diff + BATCH;                       // [49152]

    prep_kernel<<<192, 256, 0, stream>>>(c1w, c2w, c3w, T);
    lstm_kernel<<<512, 256, 0, stream>>>(rank_q, qlen, Wih_f, Whh_f, bih_f, bhh_f,
                                         Wih_b, Whh_b, bih_b, bhh_b, embq);
    score_kernel<<<BATCH / 16, 256, 0, stream>>>(r_idx, a_idx, acc_idx, ru, au, embq, T,
                                                 c1b, c2b, c3b, fc1w, fc2w, diff);
    reduce_kernel<<<1, 256, 0, stream>>>(diff, (float*)d_out);
}

// Round 6
// 95.265 us; speedup vs baseline: 5.3540x; 1.0158x over previous
//
#include <hip/hip_runtime.h>
#include <hip/hip_bf16.h>

#define LSEQ 50
#define BATCH 4096

typedef __attribute__((ext_vector_type(8))) short bf16x8;
typedef __attribute__((ext_vector_type(4))) float f32x4;

__device__ __forceinline__ unsigned cvtpk(float lo, float hi) {
    unsigned r;
    asm("v_cvt_pk_bf16_f32 %0, %1, %2" : "=v"(r) : "v"(lo), "v"(hi));
    return r;
}
__device__ __forceinline__ bf16x8 pack8(float4 a, float4 b) {
    uint4 u;
    u.x = cvtpk(a.x, a.y); u.y = cvtpk(a.z, a.w);
    u.z = cvtpk(b.x, b.y); u.w = cvtpk(b.z, b.w);
    return __builtin_bit_cast(bf16x8, u);
}
__device__ __forceinline__ float fsigm(float x) {
    return __builtin_amdgcn_rcpf(1.0f + __builtin_amdgcn_exp2f(-1.44269504f * x));
}
__device__ __forceinline__ float ftanh(float x) {
    float e = __builtin_amdgcn_exp2f(2.88539008f * x);
    return 1.0f - 2.0f * __builtin_amdgcn_rcpf(e + 1.0f);
}

// Counting-sort examples by qlen (50 bins). Within-bin order is atomic-
// nondeterministic, but the output is permutation-invariant: each example's
// LSTM arithmetic and output row are independent of which block hosts it.
__global__ __launch_bounds__(256)
void sort_kernel(const int* __restrict__ qlen, int* __restrict__ perm)
{
    __shared__ int base[64];
    const int tid = threadIdx.x;
    if (tid < 64) base[tid] = 0;
    __syncthreads();
    for (int i = tid; i < BATCH; i += 256) atomicAdd(&base[qlen[i]], 1);
    __syncthreads();
    if (tid == 0) {
        int s = 0;
        for (int v = 0; v < 50; ++v) { int c = base[v]; base[v] = s; s += c; }
    }
    __syncthreads();
    for (int i = tid; i < BATCH; i += 256) {
        int pos = atomicAdd(&base[qlen[i]], 1);
        perm[pos] = i;
    }
}

// One block = 16 length-sorted examples, one direction. Early exit:
// fwd runs max(len) steps, bwd runs 51-min(len>0) steps (t: 49 down to
// len-1). Alternating group map pairs short with long blocks so
// co-resident blocks sum to ~51 steps under either CU-packing order.
__global__ __launch_bounds__(256, 2)
void lstm_kernel(const float* __restrict__ rank_q, const int* __restrict__ qlen,
                 const int* __restrict__ perm,
                 const float* __restrict__ Wih_f, const float* __restrict__ Whh_f,
                 const float* __restrict__ bih_f, const float* __restrict__ bhh_f,
                 const float* __restrict__ Wih_b, const float* __restrict__ Whh_b,
                 const float* __restrict__ bih_b, const float* __restrict__ bhh_b,
                 float* __restrict__ embq)
{
    const int blk = blockIdx.x;
    const int dir = blk >> 8;             // 0 = forward, 1 = backward
    const int bb  = blk & 255;
    const int grp = (bb & 1) ? (255 - (bb >> 1)) : (bb >> 1);  // short/long interleave
    const int b0  = grp << 4;
    const int tid = threadIdx.x;
    const int wv  = tid >> 6;
    const int ln  = tid & 63;
    const int lm  = ln & 15;
    const int lq  = ln >> 4;
    const int m   = (wv << 4) + lm;

    const float* Wih = dir ? Wih_b : Wih_f;
    const float* Whh = dir ? Whh_b : Whh_f;
    const float* bih = dir ? bih_b : bih_f;
    const float* bhh = dir ? bhh_b : bhh_f;

    __shared__ __align__(16) unsigned short xbuf[3][16][136];  // triple buffer
    __shared__ __align__(16) unsigned short hbuf[2][16][72];
    __shared__ int len_s[16];

    if (tid < 16) len_s[tid] = qlen[perm[b0 + tid]];
    for (int i = tid; i < 16 * 72; i += 256) ((unsigned short*)hbuf)[i] = 0;

    bf16x8 bfrag[4][6];
    float bias[4];
    #pragma unroll
    for (int j = 0; j < 4; ++j) {
        const int n = (j << 6) + m;
        bias[j] = bih[n] + bhh[n];
        #pragma unroll
        for (int s = 0; s < 6; ++s) {
            const int kb = (s << 5) + (lq << 3);
            const float* src = (s < 4) ? (Wih + n * 128 + kb)
                                       : (Whh + n * 64 + (kb - 128));
            bfrag[j][s] = pack8(*(const float4*)src, *(const float4*)(src + 4));
        }
    }

    int exq[4], len_e[4];
    #pragma unroll
    for (int r = 0; r < 4; ++r) {
        exq[r]   = perm[b0 + (lq << 2) + r];
        len_e[r] = qlen[exq[r]];
    }

    float cst[4]  = {0.f, 0.f, 0.f, 0.f};
    float qval[4] = {0.f, 0.f, 0.f, 0.f};

    const int se  = tid >> 4;
    const int exs = perm[b0 + se];
    const int sd  = (tid & 15) << 3;
    const int tstep = dir ? -128 : 128;
    const float* gp = rank_q + ((size_t)exs * LSEQ + (dir ? LSEQ - 1 : 0)) * 128 + sd;

    __syncthreads();                       // len_s + hbuf zeros visible

    int steps;
    if (dir == 0) {
        int mx = 0;
        #pragma unroll
        for (int i = 0; i < 16; ++i) mx = max(mx, len_s[i]);
        steps = mx;                        // t = 0 .. maxlen-1
    } else {
        int mn = 51;
        #pragma unroll
        for (int i = 0; i < 16; ++i) { int l = len_s[i]; mn = min(mn, l ? l : 51); }
        steps = (mn == 51) ? 0 : 51 - mn;  // t = 49 down to minlen-1
    }

    if (steps > 0) {
        {   // stage x(it=0) -> xbuf[0], x(it=1) -> xbuf[1]
            float4 a0 = *(const float4*)gp, b0v = *(const float4*)(gp + 4); gp += tstep;
            float4 a1 = *(const float4*)gp, b1v = *(const float4*)(gp + 4); gp += tstep;
            *(bf16x8*)&xbuf[0][se][sd] = pack8(a0, b0v);
            *(bf16x8*)&xbuf[1][se][sd] = pack8(a1, b1v);
        }
        // held prefetch of x(2): issued a full step before its LDS store
        float4 ha, hb2;
        if (3 <= steps) { ha = *(const float4*)gp; hb2 = *(const float4*)(gp + 4); gp += tstep; }
        __syncthreads();

        const int xoff = lm * 136 + (lq << 3);
        const int hoff = lm * 72 + (lq << 3);

        f32x4 accx[4];
        {
            const unsigned short* xb = &xbuf[0][0][0];
            bf16x8 x0 = *(const bf16x8*)(xb + xoff);
            bf16x8 x1 = *(const bf16x8*)(xb + xoff + 32);
            bf16x8 x2 = *(const bf16x8*)(xb + xoff + 64);
            bf16x8 x3 = *(const bf16x8*)(xb + xoff + 96);
            #pragma unroll
            for (int j = 0; j < 4; ++j) {
                f32x4 a = {bias[j], bias[j], bias[j], bias[j]};
                a = __builtin_amdgcn_mfma_f32_16x16x32_bf16(x0, bfrag[j][0], a, 0, 0, 0);
                a = __builtin_amdgcn_mfma_f32_16x16x32_bf16(x1, bfrag[j][1], a, 0, 0, 0);
                a = __builtin_amdgcn_mfma_f32_16x16x32_bf16(x2, bfrag[j][2], a, 0, 0, 0);
                a = __builtin_amdgcn_mfma_f32_16x16x32_bf16(x3, bfrag[j][3], a, 0, 0, 0);
                accx[j] = a;
            }
        }

        int r1 = 1, w2 = 2;
        for (int it = 0; it < steps; ++it) {
            const int t   = dir ? (LSEQ - 1 - it) : it;
            const int rbh = it & 1;
            const int wbh = rbh ^ 1;

            // issue load of x(it+3) (consumed/stored next iteration)
            float4 na, nb;
            const bool nv = (it + 4 <= steps);
            if (nv) { na = *(const float4*)gp; nb = *(const float4*)(gp + 4); gp += tstep; }

            // h-part: 2-deep MFMA chain on top of pipelined acc_x
            const unsigned short* hb = &hbuf[rbh][0][0];
            bf16x8 ah0 = *(const bf16x8*)(hb + hoff);
            bf16x8 ah1 = *(const bf16x8*)(hb + hoff + 32);
            f32x4 gate[4];
            #pragma unroll
            for (int j = 0; j < 4; ++j) {
                f32x4 a = __builtin_amdgcn_mfma_f32_16x16x32_bf16(ah0, bfrag[j][4], accx[j], 0, 0, 0);
                gate[j]  = __builtin_amdgcn_mfma_f32_16x16x32_bf16(ah1, bfrag[j][5], a, 0, 0, 0);
            }

            // acc_x for it+1 (independent; fills the nonlin/stall shadow)
            if (it + 1 < steps) {
                const unsigned short* xb = &xbuf[r1][0][0];
                bf16x8 x0 = *(const bf16x8*)(xb + xoff);
                bf16x8 x1 = *(const bf16x8*)(xb + xoff + 32);
                bf16x8 x2 = *(const bf16x8*)(xb + xoff + 64);
                bf16x8 x3 = *(const bf16x8*)(xb + xoff + 96);
                #pragma unroll
                for (int j = 0; j < 4; ++j) {
                    f32x4 a = {bias[j], bias[j], bias[j], bias[j]};
                    a = __builtin_amdgcn_mfma_f32_16x16x32_bf16(x0, bfrag[j][0], a, 0, 0, 0);
                    a = __builtin_amdgcn_mfma_f32_16x16x32_bf16(x1, bfrag[j][1], a, 0, 0, 0);
                    a = __builtin_amdgcn_mfma_f32_16x16x32_bf16(x2, bfrag[j][2], a, 0, 0, 0);
                    a = __builtin_amdgcn_mfma_f32_16x16x32_bf16(x3, bfrag[j][3], a, 0, 0, 0);
                    accx[j] = a;
                }
            }

            float hn[4];
            #pragma unroll
            for (int r = 0; r < 4; ++r) {
                float ig = fsigm(gate[0][r]);
                float fg = fsigm(gate[1][r]);
                float gg = ftanh(gate[2][r]);
                float og = fsigm(gate[3][r]);
                float cn = fg * cst[r] + ig * gg;
                cst[r] = cn;
                hn[r] = og * ftanh(cn);
                if (t == len_e[r] - 1) qval[r] = hn[r];
            }
            const unsigned u01 = cvtpk(hn[0], hn[1]);
            const unsigned u23 = cvtpk(hn[2], hn[3]);
            hbuf[wbh][(lq << 2) + 0][m] = (unsigned short)u01;
            hbuf[wbh][(lq << 2) + 1][m] = (unsigned short)(u01 >> 16);
            hbuf[wbh][(lq << 2) + 2][m] = (unsigned short)u23;
            hbuf[wbh][(lq << 2) + 3][m] = (unsigned short)(u23 >> 16);

            if (it + 3 <= steps) *(bf16x8*)&xbuf[w2][se][sd] = pack8(ha, hb2);
            ha = na; hb2 = nb;

            __syncthreads();
            r1 = (r1 == 2) ? 0 : r1 + 1;
            w2 = (w2 == 2) ? 0 : w2 + 1;
        }
    }

    #pragma unroll
    for (int r = 0; r < 4; ++r)
        embq[(size_t)exq[r] * 128 + (dir << 6) + m] = qval[r];
}

// ---- prep: transpose conv weights to [m][j][c][4] (coalesced lane=c reads)
__global__ __launch_bounds__(256)
void prep_kernel(const float* __restrict__ c1w, const float* __restrict__ c2w,
                 const float* __restrict__ c3w, float* __restrict__ T)
{
    const int id = blockIdx.x * 256 + threadIdx.x;   // 49152
    const int m  = id >> 13;
    const int rem = id & 8191;
    const int j  = rem >> 8;
    const int q  = rem & 255;
    const int c  = q >> 2;
    const int d  = (j << 2) + (q & 3);
    const float* src;
    switch (m) {
        case 0:  src = c1w + c * 128 + d;       break;
        case 1:  src = c2w + c * 256 + d;       break;
        case 2:  src = c2w + c * 256 + 128 + d; break;
        case 3:  src = c3w + c * 384 + d;       break;
        case 4:  src = c3w + c * 384 + 128 + d; break;
        default: src = c3w + c * 384 + 256 + d; break;
    }
    T[id] = *src;
}

__global__ __launch_bounds__(256)
void score_kernel(const int* __restrict__ r_idx, const int* __restrict__ a_idx,
                  const int* __restrict__ acc_idx,
                  const float* __restrict__ ru, const float* __restrict__ au,
                  const float* __restrict__ embq, const float* __restrict__ T,
                  const float* __restrict__ c1b, const float* __restrict__ c2b,
                  const float* __restrict__ c3b,
                  const float* __restrict__ fc1w, const float* __restrict__ fc2w,
                  float* __restrict__ diff)
{
    const int tid = threadIdx.x;
    const int wv  = tid >> 6;
    const int c   = tid & 63;
    const int b0  = blockIdx.x << 4;

    __shared__ __align__(16) float emb[64][132];
    {
        const int row = tid & 63;
        const int e   = row >> 2, v = row & 3;
        const int seg = (tid >> 6) << 5;
        const int bb  = b0 + e;
        const float* src = (v == 0) ? ru   + (size_t)r_idx[bb]   * 128 :
                           (v == 1) ? embq + (size_t)bb          * 128 :
                           (v == 2) ? au   + (size_t)a_idx[bb]   * 128 :
                                      au   + (size_t)acc_idx[bb] * 128;
        #pragma unroll
        for (int i = 0; i < 8; ++i) {
            float4 x = *(const float4*)(src + seg + (i << 2));
            *(float4*)&emb[row][seg + (i << 2)] = x;
        }
    }
    __syncthreads();

    float acc[4][9];
    #pragma unroll
    for (int e = 0; e < 4; ++e)
        #pragma unroll
        for (int k = 0; k < 9; ++k) acc[e][k] = 0.f;

    const float4* Tq = (const float4*)T;
    for (int j = 0; j < 32; ++j) {
        const float4* wq = Tq + j * 64 + c;
        const float4 w1  = wq[0];
        const float4 w20 = wq[2048];
        const float4 w21 = wq[4096];
        const float4 w30 = wq[6144];
        const float4 w31 = wq[8192];
        const float4 w32 = wq[10240];
        const int jd = j << 2;
        #pragma unroll
        for (int e = 0; e < 4; ++e) {
            const int br = ((wv << 2) + e) << 2;
            const float4 er = *(const float4*)&emb[br + 0][jd];
            const float4 eq = *(const float4*)&emb[br + 1][jd];
            const float4 ea = *(const float4*)&emb[br + 2][jd];
            const float4 ex = *(const float4*)&emb[br + 3][jd];
            acc[e][0] += w1.x*ea.x  + w1.y*ea.y  + w1.z*ea.z  + w1.w*ea.w;
            acc[e][1] += w1.x*ex.x  + w1.y*ex.y  + w1.z*ex.z  + w1.w*ex.w;
            acc[e][2] += w20.x*eq.x + w20.y*eq.y + w20.z*eq.z + w20.w*eq.w;
            acc[e][3] += w21.x*ea.x + w21.y*ea.y + w21.z*ea.z + w21.w*ea.w;
            acc[e][4] += w21.x*ex.x + w21.y*ex.y + w21.z*ex.z + w21.w*ex.w;
            acc[e][5] += w30.x*er.x + w30.y*er.y + w30.z*er.z + w30.w*er.w;
            acc[e][6] += w31.x*eq.x + w31.y*eq.y + w31.z*eq.z + w31.w*eq.w;
            acc[e][7] += w32.x*ea.x + w32.y*ea.y + w32.z*ea.z + w32.w*ea.w;
            acc[e][8] += w32.x*ex.x + w32.y*ex.y + w32.z*ex.z + w32.w*ex.w;
        }
    }

    const float b1 = c1b[c], b2 = c2b[c], b3 = c3b[c], f2 = fc2w[c];
    const float f12 = fc1w[2], f14 = fc1w[4], f15 = fc1w[5];
    #pragma unroll
    for (int e = 0; e < 4; ++e) {
        const float r1 = fmaxf(acc[e][0] + b1, 0.f) - fmaxf(acc[e][1] + b1, 0.f);
        const float r2 = fmaxf(acc[e][2] + acc[e][3] + b2, 0.f)
                       - fmaxf(acc[e][2] + acc[e][4] + b2, 0.f);
        const float r3 = fmaxf(acc[e][5] + acc[e][6] + acc[e][7] + b3, 0.f)
                       - fmaxf(acc[e][5] + acc[e][6] + acc[e][8] + b3, 0.f);
        float term = f2 * (f12 * r1 + f14 * r2 + f15 * r3);
        #pragma unroll
        for (int off = 32; off; off >>= 1) term += __shfl_down(term, off);
        if (c == 0) diff[b0 + (wv << 2) + e] = term;
    }
}

__global__ void reduce_kernel(const float* __restrict__ diff, float* __restrict__ out)
{
    __shared__ float s[256];
    const int tid = threadIdx.x;
    float v = 0.f;
    for (int i = tid; i < BATCH; i += 256) v += diff[i];
    s[tid] = v;
    __syncthreads();
    for (int st = 128; st > 0; st >>= 1) {
        if (tid < st) s[tid] += s[tid + st];
        __syncthreads();
    }
    if (tid == 0) out[0] = s[0];
}

extern "C" void kernel_launch(void* const* d_in, const int* in_sizes, int n_in,
                              void* d_out, int out_size, void* d_ws, size_t ws_size,
                              hipStream_t stream) {
    (void)in_sizes; (void)n_in; (void)out_size; (void)ws_size;
    const int*   r_idx   = (const int*)d_in[0];
    const int*   a_idx   = (const int*)d_in[1];
    const int*   acc_idx = (const int*)d_in[2];
    const float* rank_q  = (const float*)d_in[3];
    const int*   qlen    = (const int*)d_in[4];
    const float* ru      = (const float*)d_in[5];
    const float* au      = (const float*)d_in[6];
    const float* Wih_f   = (const float*)d_in[7];
    const float* Whh_f   = (const float*)d_in[8];
    const float* bih_f   = (const float*)d_in[9];
    const float* bhh_f   = (const float*)d_in[10];
    const float* Wih_b   = (const float*)d_in[11];
    const float* Whh_b   = (const float*)d_in[12];
    const float* bih_b   = (const float*)d_in[13];
    const float* bhh_b   = (const float*)d_in[14];
    const float* c1w     = (const float*)d_in[15];
    const float* c1b     = (const float*)d_in[16];
    const float* c2w     = (const float*)d_in[17];
    const float* c2b     = (const float*)d_in[18];
    const float* c3w     = (const float*)d_in[19];
    const float* c3b     = (const float*)d_in[20];
    const float* fc1w    = (const float*)d_in[21];
    const float* fc2w    = (const float*)d_in[23];

    float* embq = (float*)d_ws;                       // [4096][128] fp32
    float* diff = embq + (size_t)BATCH * 128;         // [4096]
    float* T    = diff + BATCH;                       // [49152]
    int*   perm = (int*)(T + 49152);                  // [4096]

    sort_kernel<<<1, 256, 0, stream>>>(qlen, perm);
    prep_kernel<<<192, 256, 0, stream>>>(c1w, c2w, c3w, T);
    lstm_kernel<<<512, 256, 0, stream>>>(rank_q, qlen, perm,
                                         Wih_f, Whh_f, bih_f, bhh_f,
                                         Wih_b, Whh_b, bih_b, bhh_b, embq);
    score_kernel<<<BATCH / 16, 256, 0, stream>>>(r_idx, a_idx, acc_idx, ru, au, embq, T,
                                                 c1b, c2b, c3b, fc1w, fc2w, diff);
    reduce_kernel<<<1, 256, 0, stream>>>(diff, (float*)d_out);
}